// Round 5
// baseline (8074.784 us; speedup 1.0000x reference)
//
#include <hip/hip_runtime.h>
#include <hip/hip_fp16.h>

#define T_ 512
#define B_ 64
#define NINP_ 512
#define NHID_ 1024
#define NWG_ 128
#define HPW_ 8      // hidden units per WG
#define NCOL_ 32    // 4 gates * HPW_
#define KH_ 1024
#define LDSK_ 1544  // padded K stride (1536 + 8) in fp16 elems
#define GSTRIDE_ 33 // padded gate-exchange stride
#define FLAGSTRIDE_ 32  // uints -> 128 B per flag line (no false sharing)

typedef _Float16 half8v __attribute__((ext_vector_type(8)));
typedef _Float16 half4v __attribute__((ext_vector_type(4)));
typedef float f32x4 __attribute__((ext_vector_type(4)));
typedef unsigned u32x4 __attribute__((ext_vector_type(4)));

__global__ void cvt_f32_to_f16(const float4* __restrict__ in, half4v* __restrict__ out, int n4) {
  int idx = blockIdx.x * blockDim.x + threadIdx.x;
  if (idx < n4) {
    float4 v = in[idx];
    half4v h;
    h[0] = (_Float16)v.x; h[1] = (_Float16)v.y; h[2] = (_Float16)v.z; h[3] = (_Float16)v.w;
    out[idx] = h;
  }
}

// h double-buffers are stored in MFMA A-FRAGMENT ORDER:
//   chunk c = wv*32 + i  (wv = consumer wave, i = k-block), 0..127
//   byte addr = c*1024 + lane*16
//   lane l of chunk c holds A[16*wv + (l&15)][32*i + (l>>4)*8 .. +7]
// Consumer: 32 contiguous 1KB CACHED loads per wave (L2 shares the broadcast
// across the XCD's 16 WGs; per-step agent-acquire fence handles staleness).
// Producer WG wg: row m's 8 fp16 -> one 16B WRITE-THROUGH (sc0 sc1) store at
// chunk (m>>4)*32 + (wg>>2), lane (m&15) + 16*(wg&3)  => data at LLC pre-flag.

__global__ void __launch_bounds__(256, 1) lstm_persist(
    const float* __restrict__ mask,
    const float* __restrict__ Wih_e, const float* __restrict__ Whh_e,
    const float* __restrict__ bih_e, const float* __restrict__ bhh_e,
    const float* __restrict__ Wih_d, const float* __restrict__ Whh_d,
    const float* __restrict__ bih_d, const float* __restrict__ bhh_d,
    const _Float16* __restrict__ xh,
    _Float16* __restrict__ hbuf0, _Float16* __restrict__ hbuf1,
    unsigned* __restrict__ bar,
    float* __restrict__ out)
{
  extern __shared__ char smem[];
  _Float16* wlds = (_Float16*)smem;                                     // NCOL_ * LDSK_ fp16
  float* glds = (float*)(smem + NCOL_ * LDSK_ * 2);                     // 64 * GSTRIDE_ f32
  float* blds = (float*)(smem + NCOL_ * LDSK_ * 2 + 64 * GSTRIDE_ * 4); // NCOL_ f32
  _Float16* hlds = (_Float16*)(smem + NCOL_ * LDSK_ * 2 + 64 * GSTRIDE_ * 4 + NCOL_ * 4); // 64*8 fp16

  const int tid = threadIdx.x;
  const int wg = blockIdx.x;
  const int lane = tid & 63;
  const int wv = tid >> 6;
  const int hbase = wg * HPW_;

  auto load_w = [&](const float* Whh, const float* Wih, const float* bih, const float* bhh) {
    for (int n = 0; n < NCOL_; ++n) {
      const int gcol = (n >> 3) * NHID_ + hbase + (n & 7);
      const float* wh = Whh + (size_t)gcol * NHID_;
      const float* wi = Wih + (size_t)gcol * NINP_;
      for (int k = tid; k < KH_; k += 256) wlds[n * LDSK_ + k] = (_Float16)wh[k];
      for (int k = tid; k < NINP_; k += 256) wlds[n * LDSK_ + KH_ + k] = (_Float16)wi[k];
    }
    if (tid < NCOL_) {
      const int gcol = (tid >> 3) * NHID_ + hbase + (tid & 7);
      blds[tid] = bih[gcol] + bhh[gcol];
    }
  };

  load_w(Whh_e, Wih_e, bih_e, bhh_e);
  __syncthreads();

  float cst[2] = {0.f, 0.f};   // fp32 cell state, per-thread slice
  float hst[2] = {0.f, 0.f};   // fp32 hidden state, per-thread slice

  // MFMA fragment roles (gfx950 16x16x32):
  //   A: lane holds A[m = lane&15][k = (lane>>4)*8 + j]
  //   B: lane holds B[n = lane&15][k = (lane>>4)*8 + j]
  //   D: lane holds D[m = (lane>>4)*4 + r][n = lane&15]
  const int mrow = 16 * wv + (lane & 15);
  const int ksub = (lane >> 4) * 8;
  const int bcol0 = lane & 15;
  const _Float16* bp0 = wlds + (size_t)bcol0 * LDSK_ + ksub;
  const _Float16* bp1 = wlds + (size_t)(bcol0 + 16) * LDSK_ + ksub;

  const int em = tid >> 2;  // elementwise batch row
  const int ej = tid & 3;

  // x-projection accumulators (computed in barrier-overlap region)
  f32x4 px0 = {0.f, 0.f, 0.f, 0.f};
  f32x4 px1 = {0.f, 0.f, 0.f, 0.f};
  auto xgemm = [&](int ti) {
    const _Float16* xp = xh + ((size_t)ti * B_ + mrow) * NINP_ + ksub;
    #pragma unroll 8
    for (int kk = 0; kk < NINP_; kk += 32) {
      half8v a = *(const half8v*)(xp + kk);
      half8v b0 = *(const half8v*)(bp0 + KH_ + kk);
      half8v b1 = *(const half8v*)(bp1 + KH_ + kk);
      px0 = __builtin_amdgcn_mfma_f32_16x16x32_f16(a, b0, px0, 0, 0, 0);
      px1 = __builtin_amdgcn_mfma_f32_16x16x32_f16(a, b1, px1, 0, 0, 0);
    }
  };
  xgemm(0);  // t = 0 x-part with encoder weights

  // producer store address (fragment layout), constant per thread
  const size_t pub_off = ((size_t)((tid >> 4) * 32 + (wg >> 2))) * 1024
                       + (size_t)((tid & 15) + 16 * (wg & 3)) * 16;

  for (int t = 0; t < 2 * T_; ++t) {
    const bool dec = (t >= T_);
    const int ti = dec ? (t - T_) : t;
    if (t == T_) {
      load_w(Whh_d, Wih_d, bih_d, bhh_d);
      __syncthreads();
      px0 = (f32x4){0.f, 0.f, 0.f, 0.f};
      px1 = (f32x4){0.f, 0.f, 0.f, 0.f};
      xgemm(0);  // decoder t=0 x-part with decoder weights
    }
    const _Float16* hprev = (t & 1) ? hbuf0 : hbuf1;
    _Float16* hnext = (t & 1) ? hbuf1 : hbuf0;

    // hoist mask load above the GEMM
    float mv = 1.f;
    if (!dec) mv = mask[ti * B_ + em];

    // ---- h-GEMM A fragments: issue ALL 32 16B CACHED loads, ONE wait ----
    // asm volatile preserves program order (compiler cannot sink them, the
    // round-2/3 failure mode). Cached: the XCD L2 turns the 16-WG broadcast
    // into ONE LLC fetch per line; staleness handled by per-step acquire
    // fence below. Layout keeps loads contiguous (1 KB per instruction).
    u32x4 ab[32];
    {
      const char* ap = (const char*)hprev + (size_t)(wv * 32) * 1024 + (size_t)lane * 16;
      #pragma unroll
      for (int q = 0; q < 8; ++q) {
        const char* base = ap + (size_t)q * 4096;
        asm volatile(
          "global_load_dwordx4 %0, %4, off\n\t"
          "global_load_dwordx4 %1, %4, off offset:1024\n\t"
          "global_load_dwordx4 %2, %4, off offset:2048\n\t"
          "global_load_dwordx4 %3, %4, off offset:3072"
          : "=&v"(ab[4 * q]), "=&v"(ab[4 * q + 1]), "=&v"(ab[4 * q + 2]), "=&v"(ab[4 * q + 3])
          : "v"(base));
      }
      asm volatile("s_waitcnt vmcnt(0)");
      __builtin_amdgcn_sched_barrier(0);  // rule #18: keep uses below the wait
    }

    f32x4 acc0 = px0, acc1 = px1;
    f32x4 acc0b = {0.f, 0.f, 0.f, 0.f};
    f32x4 acc1b = {0.f, 0.f, 0.f, 0.f};
    #pragma unroll
    for (int i = 0; i < 32; i += 2) {
      half8v a0 = __builtin_bit_cast(half8v, ab[i]);
      half8v b00 = *(const half8v*)(bp0 + 32 * i);
      half8v b10 = *(const half8v*)(bp1 + 32 * i);
      acc0  = __builtin_amdgcn_mfma_f32_16x16x32_f16(a0, b00, acc0, 0, 0, 0);
      acc1  = __builtin_amdgcn_mfma_f32_16x16x32_f16(a0, b10, acc1, 0, 0, 0);
      half8v a1 = __builtin_bit_cast(half8v, ab[i + 1]);
      half8v b01 = *(const half8v*)(bp0 + 32 * (i + 1));
      half8v b11 = *(const half8v*)(bp1 + 32 * (i + 1));
      acc0b = __builtin_amdgcn_mfma_f32_16x16x32_f16(a1, b01, acc0b, 0, 0, 0);
      acc1b = __builtin_amdgcn_mfma_f32_16x16x32_f16(a1, b11, acc1b, 0, 0, 0);
    }
    acc0 = acc0 + acc0b;
    acc1 = acc1 + acc1b;

    // gate exchange via LDS (D-layout -> per-(m,j) threads)
    #pragma unroll
    for (int r = 0; r < 4; ++r) {
      const int m = 16 * wv + (lane >> 4) * 4 + r;
      glds[m * GSTRIDE_ + bcol0] = acc0[r];
      glds[m * GSTRIDE_ + 16 + bcol0] = acc1[r];
    }
    __syncthreads();

    #pragma unroll
    for (int p = 0; p < 2; ++p) {
      const int j = ej + 4 * p;
      const float gi = glds[em * GSTRIDE_ + j]      + blds[j];
      const float gf = glds[em * GSTRIDE_ + 8 + j]  + blds[8 + j];
      const float gg = glds[em * GSTRIDE_ + 16 + j] + blds[16 + j];
      const float go = glds[em * GSTRIDE_ + 24 + j] + blds[24 + j];
      const float iv = 1.f / (1.f + expf(-gi));
      const float fv = 1.f / (1.f + expf(-gf));
      const float gv = tanhf(gg);
      const float ov = 1.f / (1.f + expf(-go));
      float cn = fv * cst[p] + iv * gv;
      float hn = ov * tanhf(cn);
      if (!dec) {
        hn = hn * mv + hst[p] * (1.f - mv);
        cn = cn * mv + cst[p] * (1.f - mv);
      }
      cst[p] = cn; hst[p] = hn;
      hlds[em * 8 + j] = (_Float16)hn;               // assemble row in LDS
      if (dec) out[((size_t)ti * B_ + em) * NHID_ + hbase + j] = hn;
    }

    if (t == 2 * T_ - 1) break;  // no publish needed after the last step

    __syncthreads();  // hlds complete

    // ---- publish h WRITE-THROUGH in fragment order (wave 0), then flag ----
    if (wv == 0) {
      u32x4 hv = *(const u32x4*)(hlds + tid * 8);
      const char* dst = (const char*)hnext + pub_off;
      asm volatile("global_store_dwordx4 %0, %1, off sc0 sc1" :: "v"(dst), "v"(hv));
      asm volatile("s_waitcnt vmcnt(0)" ::: "memory");  // h at LLC before flag
      if (tid == 0)
        __hip_atomic_store(&bar[wg * FLAGSTRIDE_], (unsigned)(t + 1),
                           __ATOMIC_RELAXED, __HIP_MEMORY_SCOPE_SYSTEM);
    }

    // overlap: next step's x-projection GEMM while other WGs arrive
    if (t + 1 != T_) {
      const int tn = (t + 1 >= T_) ? (t + 1 - T_) : (t + 1);
      px0 = (f32x4){0.f, 0.f, 0.f, 0.f};
      px1 = (f32x4){0.f, 0.f, 0.f, 0.f};
      xgemm(tn);
    }

    // distributed poll: lanes of waves 0-1 each watch one WG's flag (bypass).
    if (tid < NWG_) {
      while (__hip_atomic_load(&bar[tid * FLAGSTRIDE_], __ATOMIC_RELAXED,
                               __HIP_MEMORY_SCOPE_SYSTEM) < (unsigned)(t + 1)) { }
    }
    // acquire: invalidate L1 (this CU) + L2 (this XCD) so the cached h loads
    // above see the freshly published LLC data. One wave per WG suffices
    // (all waves share the CU's L1); round-1 empirically validated this shape.
    if (tid == 0) __builtin_amdgcn_fence(__ATOMIC_ACQUIRE, "agent");
    __syncthreads();
    __builtin_amdgcn_sched_barrier(0);  // nothing hoists above the fence
  }
}

extern "C" void kernel_launch(void* const* d_in, const int* in_sizes, int n_in,
                              void* d_out, int out_size, void* d_ws, size_t ws_size,
                              hipStream_t stream) {
  const float* input = (const float*)d_in[0];
  const float* mask  = (const float*)d_in[1];
  const float* Wih_e = (const float*)d_in[2];
  const float* Whh_e = (const float*)d_in[3];
  const float* bih_e = (const float*)d_in[4];
  const float* bhh_e = (const float*)d_in[5];
  const float* Wih_d = (const float*)d_in[6];
  const float* Whh_d = (const float*)d_in[7];
  const float* bih_d = (const float*)d_in[8];
  const float* bhh_d = (const float*)d_in[9];
  float* out = (float*)d_out;
  char* ws = (char*)d_ws;

  unsigned* bar = (unsigned*)ws;                       // 128 flag lines * 128 B = 16 KB
  _Float16* hbuf0 = (_Float16*)(ws + 16384);
  _Float16* hbuf1 = hbuf0 + B_ * NHID_;
  _Float16* xh = (_Float16*)(ws + 16384 + 2 * B_ * NHID_ * 2);

  // zero flags + both h double-buffers (ws is poisoned 0xAA before each call)
  hipMemsetAsync(ws, 0, 16384 + 2 * B_ * NHID_ * 2, stream);

  const int n4 = T_ * B_ * NINP_ / 4;
  cvt_f32_to_f16<<<n4 / 256, 256, 0, stream>>>((const float4*)input, (half4v*)xh, n4);

  const size_t lds_bytes = (size_t)NCOL_ * LDSK_ * 2 + 64 * GSTRIDE_ * 4 + NCOL_ * 4 + 64 * HPW_ * 2;
  hipFuncSetAttribute((const void*)lstm_persist, hipFuncAttributeMaxDynamicSharedMemorySize, (int)lds_bytes);

  void* args[] = { (void*)&mask, (void*)&Wih_e, (void*)&Whh_e, (void*)&bih_e, (void*)&bhh_e,
                   (void*)&Wih_d, (void*)&Whh_d, (void*)&bih_d, (void*)&bhh_d,
                   (void*)&xh, (void*)&hbuf0, (void*)&hbuf1, (void*)&bar, (void*)&out };
  hipLaunchCooperativeKernel((void*)lstm_persist, dim3(NWG_), dim3(256), args,
                             (unsigned)lds_bytes, stream);
}

// Round 7
// 7242.931 us; speedup vs baseline: 1.1149x; 1.1149x over previous
//
#include <hip/hip_runtime.h>
#include <hip/hip_fp16.h>

#define T_ 512
#define B_ 64
#define NINP_ 512
#define NHID_ 1024
#define NWG_ 128
#define HPW_ 8      // hidden units per WG
#define NCOL_ 32    // 4 gates * HPW_
#define GSTRIDE_ 33 // padded gate-exchange stride
#define FLAGSTRIDE_ 32  // uints -> 128 B per flag line (no false sharing)

typedef _Float16 half8v __attribute__((ext_vector_type(8)));
typedef _Float16 half4v __attribute__((ext_vector_type(4)));
typedef float f32x4 __attribute__((ext_vector_type(4)));
typedef unsigned u32x4 __attribute__((ext_vector_type(4)));

__global__ void cvt_f32_to_f16(const float4* __restrict__ in, half4v* __restrict__ out, int n4) {
  int idx = blockIdx.x * blockDim.x + threadIdx.x;
  if (idx < n4) {
    float4 v = in[idx];
    half4v h;
    h[0] = (_Float16)v.x; h[1] = (_Float16)v.y; h[2] = (_Float16)v.z; h[3] = (_Float16)v.w;
    out[idx] = h;
  }
}

// h double-buffers in MFMA A-FRAGMENT ORDER (round-4 layout, unchanged):
//   chunk c = wv*32 + i, byte addr = c*1024 + lane*16
//   lane l of chunk c holds A[16*wv + (l&15)][32*i + (l>>4)*8 .. +7]
//
// Weights in FRAGMENT-ORDERED LDS (new this round — kills bank conflicts):
//   one frag = 512 halfs = 1024 B; lane l's 8 halfs at frag_base + l*8
//   frag content: W[gcol(tt*16 + (l&15))][32*K + (l>>4)*8 + j], j=0..7
//   h-frags (Whh): f = 2*K + tt        at wlds + f*512        (f in [0,64))
//   x-frags (Wih): g = tt*16 + K       at wlds + (64+g)*512   (g in [0,32))
//   Reads are lane-contiguous 16 B (ds_read_b128 reference pattern, 0-conflict).

__global__ void __launch_bounds__(256, 1) lstm_persist(
    const float* __restrict__ mask,
    const float* __restrict__ Wih_e, const float* __restrict__ Whh_e,
    const float* __restrict__ bih_e, const float* __restrict__ bhh_e,
    const float* __restrict__ Wih_d, const float* __restrict__ Whh_d,
    const float* __restrict__ bih_d, const float* __restrict__ bhh_d,
    const _Float16* __restrict__ xh,
    _Float16* __restrict__ hbuf0, _Float16* __restrict__ hbuf1,
    unsigned* __restrict__ bar,
    float* __restrict__ out)
{
  extern __shared__ char smem[];
  _Float16* wlds = (_Float16*)smem;                         // 96 frags * 1024 B = 98304
  float* glds = (float*)(smem + 98304);                     // 64 * GSTRIDE_ f32 = 8448
  float* blds = (float*)(smem + 98304 + 8448);              // NCOL_ f32 = 128
  _Float16* hlds = (_Float16*)(smem + 98304 + 8448 + 128);  // 64*8 fp16 = 1024

  const int tid = threadIdx.x;
  const int wg = blockIdx.x;
  const int lane = tid & 63;
  const int wv = tid >> 6;
  const int hbase = wg * HPW_;

  // MFMA fragment roles (gfx950 16x16x32):
  //   A: lane holds A[m = lane&15][k = (lane>>4)*8 + j]
  //   B: lane holds B[n = lane&15][k = (lane>>4)*8 + j]
  //   D: lane holds D[m = (lane>>4)*4 + r][n = lane&15]
  const int mrow = 16 * wv + (lane & 15);
  const int ksub = (lane >> 4) * 8;
  const int bcol0 = lane & 15;

  // frag-ordered weight loader (each wave stages 24 of the 96 frags)
  auto load_w = [&](const float* Whh, const float* Wih, const float* bih, const float* bhh) {
    for (int f = wv; f < 96; f += 4) {
      int tt, K;
      const float* src;
      if (f < 64) {
        K = f >> 1; tt = f & 1;
        const int n = tt * 16 + bcol0;
        const int gcol = (n >> 3) * NHID_ + hbase + (n & 7);
        src = Whh + (size_t)gcol * NHID_ + 32 * K + ksub;
      } else {
        const int g = f - 64; tt = g >> 4; K = g & 15;
        const int n = tt * 16 + bcol0;
        const int gcol = (n >> 3) * NHID_ + hbase + (n & 7);
        src = Wih + (size_t)gcol * NINP_ + 32 * K + ksub;
      }
      float4 a0 = *(const float4*)src;
      float4 a1 = *(const float4*)(src + 4);
      half8v h;
      h[0]=(_Float16)a0.x; h[1]=(_Float16)a0.y; h[2]=(_Float16)a0.z; h[3]=(_Float16)a0.w;
      h[4]=(_Float16)a1.x; h[5]=(_Float16)a1.y; h[6]=(_Float16)a1.z; h[7]=(_Float16)a1.w;
      *(half8v*)(wlds + f * 512 + lane * 8) = h;
    }
    if (tid < NCOL_) {
      const int gcol = (tid >> 3) * NHID_ + hbase + (tid & 7);
      blds[tid] = bih[gcol] + bhh[gcol];
    }
  };

  load_w(Whh_e, Wih_e, bih_e, bhh_e);
  __syncthreads();

  float cst[2] = {0.f, 0.f};   // fp32 cell state, per-thread slice
  float hst[2] = {0.f, 0.f};   // fp32 hidden state, per-thread slice

  const _Float16* hwl = wlds + lane * 8;             // h-frag base (offsets fit imm)
  const _Float16* xwl = wlds + 64 * 512 + lane * 8;  // x-frag base

  const int em = tid >> 2;  // elementwise batch row
  const int ej = tid & 3;

  // x-projection accumulators (computed in barrier-overlap region)
  f32x4 px0 = {0.f, 0.f, 0.f, 0.f};
  f32x4 px1 = {0.f, 0.f, 0.f, 0.f};
  auto xgemm = [&](int ti) {
    const _Float16* xp = xh + ((size_t)ti * B_ + mrow) * NINP_ + ksub;
    #pragma unroll
    for (int ik = 0; ik < 16; ++ik) {
      half8v a = *(const half8v*)(xp + 32 * ik);
      half8v b0 = *(const half8v*)(xwl + ik * 512);          // tile0
      half8v b1 = *(const half8v*)(xwl + (16 + ik) * 512);   // tile1
      px0 = __builtin_amdgcn_mfma_f32_16x16x32_f16(a, b0, px0, 0, 0, 0);
      px1 = __builtin_amdgcn_mfma_f32_16x16x32_f16(a, b1, px1, 0, 0, 0);
    }
  };
  xgemm(0);  // t = 0 x-part with encoder weights

  // producer store address (fragment layout), constant per thread
  const size_t pub_off = ((size_t)((tid >> 4) * 32 + (wg >> 2))) * 1024
                       + (size_t)((tid & 15) + 16 * (wg & 3)) * 16;

  for (int t = 0; t < 2 * T_; ++t) {
    const bool dec = (t >= T_);
    const int ti = dec ? (t - T_) : t;
    if (t == T_) {
      load_w(Whh_d, Wih_d, bih_d, bhh_d);
      __syncthreads();
      px0 = (f32x4){0.f, 0.f, 0.f, 0.f};
      px1 = (f32x4){0.f, 0.f, 0.f, 0.f};
      xgemm(0);  // decoder t=0 x-part with decoder weights
    }
    const _Float16* hprev = (t & 1) ? hbuf0 : hbuf1;
    _Float16* hnext = (t & 1) ? hbuf1 : hbuf0;

    // hoist mask load above the GEMM
    float mv = 1.f;
    if (!dec) mv = mask[ti * B_ + em];

    // ---- h-GEMM A fragments: issue ALL 32 16B bypass loads, ONE wait ----
    // asm volatile preserves program order (round-3 fix); sc0 sc1 reads the
    // memory-side LLC directly (never stale; round-4 validated).
    u32x4 ab[32];
    {
      const char* ap = (const char*)hprev + (size_t)(wv * 32) * 1024 + (size_t)lane * 16;
      #pragma unroll
      for (int q = 0; q < 8; ++q) {
        const char* base = ap + (size_t)q * 4096;
        asm volatile(
          "global_load_dwordx4 %0, %4, off sc0 sc1\n\t"
          "global_load_dwordx4 %1, %4, off offset:1024 sc0 sc1\n\t"
          "global_load_dwordx4 %2, %4, off offset:2048 sc0 sc1\n\t"
          "global_load_dwordx4 %3, %4, off offset:3072 sc0 sc1"
          : "=&v"(ab[4 * q]), "=&v"(ab[4 * q + 1]), "=&v"(ab[4 * q + 2]), "=&v"(ab[4 * q + 3])
          : "v"(base));
      }
      asm volatile("s_waitcnt vmcnt(0)");
      __builtin_amdgcn_sched_barrier(0);  // rule #18: keep uses below the wait
    }

    // ---- h-GEMM: B from conflict-free frag-ordered LDS ----
    f32x4 acc0 = px0, acc1 = px1;
    f32x4 acc0b = {0.f, 0.f, 0.f, 0.f};
    f32x4 acc1b = {0.f, 0.f, 0.f, 0.f};
    #pragma unroll
    for (int i = 0; i < 32; i += 2) {
      half8v a0 = __builtin_bit_cast(half8v, ab[i]);
      half8v b00 = *(const half8v*)(hwl + (2 * i) * 512);
      half8v b10 = *(const half8v*)(hwl + (2 * i + 1) * 512);
      acc0  = __builtin_amdgcn_mfma_f32_16x16x32_f16(a0, b00, acc0, 0, 0, 0);
      acc1  = __builtin_amdgcn_mfma_f32_16x16x32_f16(a0, b10, acc1, 0, 0, 0);
      half8v a1 = __builtin_bit_cast(half8v, ab[i + 1]);
      half8v b01 = *(const half8v*)(hwl + (2 * i + 2) * 512);
      half8v b11 = *(const half8v*)(hwl + (2 * i + 3) * 512);
      acc0b = __builtin_amdgcn_mfma_f32_16x16x32_f16(a1, b01, acc0b, 0, 0, 0);
      acc1b = __builtin_amdgcn_mfma_f32_16x16x32_f16(a1, b11, acc1b, 0, 0, 0);
    }
    acc0 = acc0 + acc0b;
    acc1 = acc1 + acc1b;

    // gate exchange via LDS (D-layout -> per-(m,j) threads)
    #pragma unroll
    for (int r = 0; r < 4; ++r) {
      const int m = 16 * wv + (lane >> 4) * 4 + r;
      glds[m * GSTRIDE_ + bcol0] = acc0[r];
      glds[m * GSTRIDE_ + 16 + bcol0] = acc1[r];
    }
    __syncthreads();

    #pragma unroll
    for (int p = 0; p < 2; ++p) {
      const int j = ej + 4 * p;
      const float gi = glds[em * GSTRIDE_ + j]      + blds[j];
      const float gf = glds[em * GSTRIDE_ + 8 + j]  + blds[8 + j];
      const float gg = glds[em * GSTRIDE_ + 16 + j] + blds[16 + j];
      const float go = glds[em * GSTRIDE_ + 24 + j] + blds[24 + j];
      const float iv = 1.f / (1.f + expf(-gi));
      const float fv = 1.f / (1.f + expf(-gf));
      const float gv = tanhf(gg);
      const float ov = 1.f / (1.f + expf(-go));
      float cn = fv * cst[p] + iv * gv;
      float hn = ov * tanhf(cn);
      if (!dec) {
        hn = hn * mv + hst[p] * (1.f - mv);
        cn = cn * mv + cst[p] * (1.f - mv);
      }
      cst[p] = cn; hst[p] = hn;
      hlds[em * 8 + j] = (_Float16)hn;               // assemble row in LDS
      if (dec) out[((size_t)ti * B_ + em) * NHID_ + hbase + j] = hn;
    }

    if (t == 2 * T_ - 1) break;  // no publish needed after the last step

    __syncthreads();  // hlds complete

    // ---- publish h write-through in fragment order (wave 0), then flag ----
    if (wv == 0) {
      u32x4 hv = *(const u32x4*)(hlds + tid * 8);
      const char* dst = (const char*)hnext + pub_off;
      asm volatile("global_store_dwordx4 %0, %1, off sc0 sc1" :: "v"(dst), "v"(hv));
      asm volatile("s_waitcnt vmcnt(0)" ::: "memory");  // h at LLC before flag
      if (tid == 0)
        __hip_atomic_store(&bar[wg * FLAGSTRIDE_], (unsigned)(t + 1),
                           __ATOMIC_RELAXED, __HIP_MEMORY_SCOPE_SYSTEM);
    }

    // overlap: next step's x-projection GEMM while other WGs arrive
    if (t + 1 != T_) {
      const int tn = (t + 1 >= T_) ? (t + 1 - T_) : (t + 1);
      px0 = (f32x4){0.f, 0.f, 0.f, 0.f};
      px1 = (f32x4){0.f, 0.f, 0.f, 0.f};
      xgemm(tn);
    }

    // distributed poll: lanes of waves 0-1 each watch one WG's flag (bypass).
    if (tid < NWG_) {
      while (__hip_atomic_load(&bar[tid * FLAGSTRIDE_], __ATOMIC_RELAXED,
                               __HIP_MEMORY_SCOPE_SYSTEM) < (unsigned)(t + 1)) { }
    }
    __syncthreads();
  }
}

extern "C" void kernel_launch(void* const* d_in, const int* in_sizes, int n_in,
                              void* d_out, int out_size, void* d_ws, size_t ws_size,
                              hipStream_t stream) {
  const float* input = (const float*)d_in[0];
  const float* mask  = (const float*)d_in[1];
  const float* Wih_e = (const float*)d_in[2];
  const float* Whh_e = (const float*)d_in[3];
  const float* bih_e = (const float*)d_in[4];
  const float* bhh_e = (const float*)d_in[5];
  const float* Wih_d = (const float*)d_in[6];
  const float* Whh_d = (const float*)d_in[7];
  const float* bih_d = (const float*)d_in[8];
  const float* bhh_d = (const float*)d_in[9];
  float* out = (float*)d_out;
  char* ws = (char*)d_ws;

  unsigned* bar = (unsigned*)ws;                       // 128 flag lines * 128 B = 16 KB
  _Float16* hbuf0 = (_Float16*)(ws + 16384);
  _Float16* hbuf1 = hbuf0 + B_ * NHID_;
  _Float16* xh = (_Float16*)(ws + 16384 + 2 * B_ * NHID_ * 2);

  // zero flags + both h double-buffers (ws is poisoned 0xAA before each call)
  hipMemsetAsync(ws, 0, 16384 + 2 * B_ * NHID_ * 2, stream);

  const int n4 = T_ * B_ * NINP_ / 4;
  cvt_f32_to_f16<<<n4 / 256, 256, 0, stream>>>((const float4*)input, (half4v*)xh, n4);

  const size_t lds_bytes = 98304 + 8448 + 128 + 1024;  // wlds + glds + blds + hlds
  hipFuncSetAttribute((const void*)lstm_persist, hipFuncAttributeMaxDynamicSharedMemorySize, (int)lds_bytes);

  void* args[] = { (void*)&mask, (void*)&Wih_e, (void*)&Whh_e, (void*)&bih_e, (void*)&bhh_e,
                   (void*)&Wih_d, (void*)&Whh_d, (void*)&bih_d, (void*)&bhh_d,
                   (void*)&xh, (void*)&hbuf0, (void*)&hbuf1, (void*)&bar, (void*)&out };
  hipLaunchCooperativeKernel((void*)lstm_persist, dim3(NWG_), dim3(256), args,
                             (unsigned)lds_bytes, stream);
}